// Round 8
// baseline (2637.859 us; speedup 1.0000x reference)
//
#include <hip/hip_runtime.h>
#include <hip/hip_bf16.h>
#include <hip/hip_fp16.h>
#include <cstdint>
#include <cstddef>

#define NN 100000
#define EE 1600000
#define GG 2048

#define NOCT 8
#define OCTW 12500                    // src rows per octant
#define SLICE_BYTES (OCTW * 256)      // 3.2 MB octant slice of H (< 4 MB L2/XCD)
#define NBLK 1024                     // 4 blocks/CU -> exactly co-resident
#define NGRPT (NBLK * 16)             // 16384 16-lane groups
#define NSLOT 7                       // ceil(NN / NGRPT): static register slots
#define NBIN (NOCT * NGRPT)           // 131072 (octant, group) bins
#define BSTR 48                       // bin pad; lambda~13, P(>=48)*NBIN ~ 1e-8
#define PFCH 25000                    // prefetch chunk/block (128 ranks per XCD)

constexpr int NB_EDGE = (EE + NN + 255) / 256;  // 6641
constexpr int NB_GEMM = NN / 16;                // 6250
constexpr int NB_OUT  = (GG + 255) / 256;       // 8

typedef float floatx4 __attribute__((ext_vector_type(4)));  // native vec for nt-store

__device__ __forceinline__ float lrelu(float v) { return v > 0.f ? v : 0.2f * v; }

__device__ __forceinline__ void nt_store4(const float4& v, float4* p) {
    floatx4 t; t.x = v.x; t.y = v.y; t.z = v.z; t.w = v.w;
    __builtin_nontemporal_store(t, (floatx4*)p);
}

// ---------------- shared GEMM body (layer GEMM + attention-logit epilogue) --
// One wave = 4 rows; x-row pointers wave-uniform (SGPR via readfirstlane).
// H/als/ald stores nontemporal: consumed once cross-XCD; keep producer L2 clean.
template <int FIN>
__device__ __forceinline__ void gemm_body(int bidx, const float* __restrict__ X,
                                          const float* __restrict__ W,
                                          const float* __restrict__ asrc,
                                          const float* __restrict__ adst,
                                          float* __restrict__ H,
                                          float* __restrict__ als,
                                          float* __restrict__ ald) {
    int j  = threadIdx.x & 63;
    int ty = threadIdx.x >> 6;
    int row = __builtin_amdgcn_readfirstlane(bidx * 16 + ty * 4);
    const float* x0 = X + (size_t)row * FIN;
    const float* x1 = x0 + FIN;
    const float* x2 = x1 + FIN;
    const float* x3 = x2 + FIN;
    float a0 = 0.f, a1 = 0.f, a2 = 0.f, a3 = 0.f;
#pragma unroll
    for (int k = 0; k < FIN; k += 4) {
        float4 xa = *(const float4*)(x0 + k);
        float4 xb = *(const float4*)(x1 + k);
        float4 xc = *(const float4*)(x2 + k);
        float4 xd = *(const float4*)(x3 + k);
        float w0 = W[(k + 0) * 64 + j];
        float w1 = W[(k + 1) * 64 + j];
        float w2 = W[(k + 2) * 64 + j];
        float w3 = W[(k + 3) * 64 + j];
        a0 += xa.x * w0 + xa.y * w1 + xa.z * w2 + xa.w * w3;
        a1 += xb.x * w0 + xb.y * w1 + xb.z * w2 + xb.w * w3;
        a2 += xc.x * w0 + xc.y * w1 + xc.z * w2 + xc.w * w3;
        a3 += xd.x * w0 + xd.y * w1 + xd.z * w2 + xd.w * w3;
    }
    __builtin_nontemporal_store(a0, &H[(size_t)(row + 0) * 64 + j]);
    __builtin_nontemporal_store(a1, &H[(size_t)(row + 1) * 64 + j]);
    __builtin_nontemporal_store(a2, &H[(size_t)(row + 2) * 64 + j]);
    __builtin_nontemporal_store(a3, &H[(size_t)(row + 3) * 64 + j]);
    float asj = asrc[j], adj = adst[j];
    float accs[4] = {a0, a1, a2, a3};
#pragma unroll
    for (int r = 0; r < 4; r++) {
        float vs = accs[r] * asj;
        float vd = accs[r] * adj;
#pragma unroll
        for (int off = 8; off > 0; off >>= 1) {
            vs += __shfl_xor(vs, off, 64);
            vd += __shfl_xor(vd, off, 64);
        }
        if ((j & 15) == 0) {
            int h = j >> 4;
            __builtin_nontemporal_store(vs, &als[(size_t)(row + r) * 4 + h]);
            __builtin_nontemporal_store(vd, &ald[(size_t)(row + r) * 4 + h]);
        }
    }
}

template <int FIN>
__global__ __launch_bounds__(256) void k_gemm(const float* __restrict__ X,
                                              const float* __restrict__ W,
                                              const float* __restrict__ asrc,
                                              const float* __restrict__ adst,
                                              float* __restrict__ H,
                                              float* __restrict__ als,
                                              float* __restrict__ ald) {
    gemm_body<FIN>(blockIdx.x, X, W, asrc, adst, H, als, ald);
}

// ---------------- single-pass (octant, dst-group) binned build --------------
// bin = src_octant*NGRPT + dst%NGRPT; entry = (src<<4) | slot (slot = dst/NGRPT,
// 0..6). One atomic pass places everything (softmax is order-invariant).
// Fused with layer-0 GEMM and out init.
__global__ __launch_bounds__(256) void k_build(const int* __restrict__ ei,
                                               int* __restrict__ cnt2,
                                               int* __restrict__ col2,
                                               int* __restrict__ ofc,
                                               int* __restrict__ ofl,
                                               const float* __restrict__ X,
                                               const float* __restrict__ W,
                                               const float* __restrict__ asrc,
                                               const float* __restrict__ adst,
                                               float* __restrict__ H,
                                               float* __restrict__ als,
                                               float* __restrict__ ald,
                                               const float* __restrict__ head_b,
                                               float* __restrict__ out) {
    int b = blockIdx.x;
    if (b < NB_EDGE) {
        int i = b * 256 + threadIdx.x;
        if (i < EE + NN) {
            int s, d;
            if (i < EE) { s = ei[i]; d = ei[EE + i]; } else { s = d = i - EE; }
            int p    = (int)((unsigned)s / OCTW);
            int gid  = (int)((unsigned)d % NGRPT);
            int slot = (int)((unsigned)d / NGRPT);
            int bin  = p * NGRPT + gid;
            int r = atomicAdd(&cnt2[bin], 1);
            int tag = (s << 4) | slot;
            if (r < BSTR) __builtin_nontemporal_store(tag, &col2[(size_t)bin * BSTR + r]);
            else { int o = atomicAdd(ofc, 1); ofl[2 * o] = s; ofl[2 * o + 1] = d; }
        }
    } else if (b < NB_EDGE + NB_GEMM) {
        gemm_body<128>(b - NB_EDGE, X, W, asrc, adst, H, als, ald);
    } else {
        int gI = (b - NB_EDGE - NB_GEMM) * 256 + threadIdx.x;
        if (gI < GG) out[gI] = head_b[0];
    }
}

// ---------------- octant-phased gather v3: static register slots ------------
// 1024 persistent blocks, 4/CU (LDS ~4 KB only). Each 16-lane group owns
// NSLOT=7 nodes in STATIC register slots. Per phase: RMW-poll soft barrier
// (atomicAdd(ctr,0) reads are RMW-coherent; bounded -> deadlock-free),
// sequential slice prefetch, flat 6-deep batched gather over the (p,gid)
// bin run, branch-free select-accumulate into the static slots.
// NO LDS writes in the loop -> no RMW serialization (round-7 fix).
__global__ __launch_bounds__(256, 4) void k_aggph2(
    const float* __restrict__ H, const float* __restrict__ als,
    const float* __restrict__ ald, const int* __restrict__ cnt2,
    const int* __restrict__ col2, const int* __restrict__ ofc,
    const int* __restrict__ ofl, const float* __restrict__ bias,
    const int* __restrict__ batch, const float* __restrict__ hw,
    float* __restrict__ out, float* __restrict__ Hout,
    int* __restrict__ ctr, int last) {
    __shared__ float adhs[16 * 16 * 4];   // [g][slot(padded 16)][hsel], 4 KB, read-only
    int tid = threadIdx.x, b = blockIdx.x;
    int g = tid >> 4, l = tid & 15, hsel = l >> 2;
    int gid = b * 16 + g;
    int rid = b >> 3;                 // rank among this XCD's 128 blocks (b&7=XCD heuristic)
    const float4* Hp = (const float4*)H + l;

    for (int k = tid; k < 16 * 16 * 4; k += 256) adhs[k] = 0.f;
    __syncthreads();
    for (int k = tid; k < 16 * NSLOT * 4; k += 256) {
        int g2 = k / (NSLOT * 4), r = k % (NSLOT * 4), t2 = r >> 2, h2 = r & 3;
        int n2 = (b * 16 + g2) + t2 * NGRPT;
        adhs[(g2 * 16 + t2) * 4 + h2] = (n2 < NN) ? ald[(size_t)n2 * 4 + h2] : 0.f;
    }
    __syncthreads();

    float4 acc[NSLOT];
    float  ssum[NSLOT];
#pragma unroll
    for (int t = 0; t < NSLOT; t++) {
        acc[t] = make_float4(0.f, 0.f, 0.f, 0.f);
        ssum[t] = 0.f;
    }

    for (int p = 0; p < NOCT; p++) {
        // soft barrier: RMW-coherent polls, bounded spin (locality-only)
        __syncthreads();
        if (tid == 0) {
            __hip_atomic_fetch_add(&ctr[p], 1, __ATOMIC_RELAXED, __HIP_MEMORY_SCOPE_AGENT);
            int polls = 0;
            while (polls++ < 8 &&
                   __hip_atomic_fetch_add(&ctr[p], 0, __ATOMIC_RELAXED,
                                          __HIP_MEMORY_SCOPE_AGENT) < NBLK)
                __builtin_amdgcn_s_sleep(2);
        }
        __syncthreads();

        // sequential slice prefetch (one 4B touch per 64B line)
        {
            const char* sb = (const char*)H + (size_t)p * SLICE_BYTES + (size_t)rid * PFCH;
            float sink = 0.f;
#pragma unroll
            for (int k = 0; k < 2; k++) {
                int off = (tid + k * 256) * 64;
                if (off < PFCH) sink += *(const float*)(sb + off);
            }
            asm volatile("" :: "v"(sink));
        }

        // flat 6-deep gather over this group's bin run
        int bin = p * NGRPT + gid;
        int cnt = cnt2[bin];
        int c = cnt < BSTR ? cnt : BSTR;
        size_t base = (size_t)bin * BSTR;
        for (int e = 0; e < c; e += 6) {
            int tg[6];
#pragma unroll
            for (int i = 0; i < 6; i++)
                tg[i] = (e + i < c) ? col2[base + e + i] : 15;  // s=0, slot=15: no match
            float w[6]; float4 hr[6]; int ti[6];
#pragma unroll
            for (int i = 0; i < 6; i++) {
                int s = tg[i] >> 4;
                ti[i] = tg[i] & 15;
                float a = als[(size_t)s * 4 + hsel];
                hr[i] = Hp[(size_t)s * 16];
                float ad = adhs[(g * 16 + ti[i]) * 4 + hsel];   // read-only LDS
                w[i] = __expf(lrelu(a + ad));   // garbage ok for pad: selected to 0 below
            }
#pragma unroll
            for (int i = 0; i < 6; i++) {
#pragma unroll
                for (int t = 0; t < NSLOT; t++) {               // static slot select
                    float wt = (ti[i] == t) ? w[i] : 0.f;
                    acc[t].x = fmaf(wt, hr[i].x, acc[t].x);
                    acc[t].y = fmaf(wt, hr[i].y, acc[t].y);
                    acc[t].z = fmaf(wt, hr[i].z, acc[t].z);
                    acc[t].w = fmaf(wt, hr[i].w, acc[t].w);
                    ssum[t] += wt;
                }
            }
        }
    }

    // overflow fallback (empty in practice; correctness only)
    int oc = *ofc;
    if (oc > 0) {
        for (int k = 0; k < oc; k++) {
            int s = ofl[2 * k], d = ofl[2 * k + 1];
            if ((int)((unsigned)d % NGRPT) == gid) {
                int td = (int)((unsigned)d / NGRPT);
                float a = als[(size_t)s * 4 + hsel];
                float4 h0 = Hp[(size_t)s * 16];
                float ad = adhs[(g * 16 + td) * 4 + hsel];
                float w0 = __expf(lrelu(a + ad));
#pragma unroll
                for (int t = 0; t < NSLOT; t++) {
                    float wt = (td == t) ? w0 : 0.f;
                    acc[t].x = fmaf(wt, h0.x, acc[t].x);
                    acc[t].y = fmaf(wt, h0.y, acc[t].y);
                    acc[t].z = fmaf(wt, h0.z, acc[t].z);
                    acc[t].w = fmaf(wt, h0.w, acc[t].w);
                    ssum[t] += wt;
                }
            }
        }
    }

    // finalize: normalize + bias + relu; store rows or head-project + pool
    float4 b4 = ((const float4*)bias)[l];
    float4 w4 = make_float4(0.f, 0.f, 0.f, 0.f);
    if (last) w4 = ((const float4*)hw)[l];
#pragma unroll
    for (int t = 0; t < NSLOT; t++) {
        int n = gid + t * NGRPT;
        if (n < NN) {
            float inv = 1.f / (ssum[t] + 1e-16f);
            float4 o;
            o.x = fmaxf(acc[t].x * inv + b4.x, 0.f);
            o.y = fmaxf(acc[t].y * inv + b4.y, 0.f);
            o.z = fmaxf(acc[t].z * inv + b4.z, 0.f);
            o.w = fmaxf(acc[t].w * inv + b4.w, 0.f);
            if (!last) {
                nt_store4(o, &((float4*)Hout)[(size_t)n * 16 + l]);
            } else {
                float tt = o.x * w4.x + o.y * w4.y + o.z * w4.z + o.w * w4.w;
#pragma unroll
                for (int off = 8; off > 0; off >>= 1) tt += __shfl_xor(tt, off, 16);
                if (l == 0) atomicAdd(&out[batch[n]], tt);
            }
        }
    }
}

// ---------------- launch -----------------------------------------------------
extern "C" void kernel_launch(void* const* d_in, const int* in_sizes, int n_in,
                              void* d_out, int out_size, void* d_ws, size_t ws_size,
                              hipStream_t stream) {
    const float* x     = (const float*)d_in[0];
    const int*   ei    = (const int*)d_in[1];
    const int*   batch = (const int*)d_in[2];
    const float* Wm[3] = {(const float*)d_in[3], (const float*)d_in[7],  (const float*)d_in[11]};
    const float* As[3] = {(const float*)d_in[4], (const float*)d_in[8],  (const float*)d_in[12]};
    const float* Ad[3] = {(const float*)d_in[5], (const float*)d_in[9],  (const float*)d_in[13]};
    const float* Bb[3] = {(const float*)d_in[6], (const float*)d_in[10], (const float*)d_in[14]};
    const float* hw = (const float*)d_in[15];
    const float* hb = (const float*)d_in[16];
    float* out = (float*)d_out;

    uint8_t* w = (uint8_t*)d_ws;
    auto alloc = [&](size_t bytes) -> void* {
        void* p = (void*)w;
        w += (bytes + 255) & ~(size_t)255;
        return p;
    };
    float* H    = (float*)alloc((size_t)NN * 64 * 4);        // ping (gather source)
    float* Bf   = (float*)alloc((size_t)NN * 64 * 4);        // pong
    float* als  = (float*)alloc((size_t)NN * 4 * 4);
    float* ald  = (float*)alloc((size_t)NN * 4 * 4);
    int*   meta = (int*)alloc((size_t)(NBIN + 64) * 4);      // cnt2 + ofc + ctr
    int*   col2 = (int*)alloc((size_t)NBIN * BSTR * 4);      // 25 MB binned CSR
    int*   ofl  = (int*)alloc((size_t)4096 * 2 * 4);

    int* cnt2 = meta;
    int* ofc  = meta + NBIN;
    int* ctr  = ofc + 8;     // 24 phase counters (3 layers x 8)

    hipMemsetAsync(meta, 0, (size_t)(NBIN + 64) * 4, stream);

    // binned build || layer-0 GEMM || out init, one grid
    k_build<<<NB_EDGE + NB_GEMM + NB_OUT, 256, 0, stream>>>(
        ei, cnt2, col2, ofc, ofl,
        x, Wm[0], As[0], Ad[0], H, als, ald, hb, out);

    // layer 0
    k_aggph2<<<NBLK, 256, 0, stream>>>(H, als, ald, cnt2, col2, ofc, ofl, Bb[0],
                                       batch, hw, out, Bf, ctr + 0, 0);
    // layer 1
    k_gemm<64><<<NB_GEMM, 256, 0, stream>>>(Bf, Wm[1], As[1], Ad[1], H, als, ald);
    k_aggph2<<<NBLK, 256, 0, stream>>>(H, als, ald, cnt2, col2, ofc, ofl, Bb[1],
                                       batch, hw, out, Bf, ctr + 8, 0);
    // layer 2
    k_gemm<64><<<NB_GEMM, 256, 0, stream>>>(Bf, Wm[2], As[2], Ad[2], H, als, ald);
    k_aggph2<<<NBLK, 256, 0, stream>>>(H, als, ald, cnt2, col2, ofc, ofl, Bb[2],
                                       batch, hw, out, H /*unused*/, ctr + 16, 1);
}

// Round 9
// 734.342 us; speedup vs baseline: 3.5921x; 3.5921x over previous
//
#include <hip/hip_runtime.h>
#include <hip/hip_bf16.h>
#include <hip/hip_fp16.h>
#include <cstdint>
#include <cstddef>

#define NN 100000
#define EE 1600000
#define GG 2048

#define NPH 4                 // dst-quartant phases for the scatter
#define QW  25000             // NN / NPH
#define SNBLK 1024            // persistent scatter blocks (trivially co-resident)

constexpr int NB_CNT  = (EE + NN + 255) / 256;  // 6641 count blocks
constexpr int NB_GEMM = NN / 16;                // 6250 gemm blocks
constexpr int SCH = (EE + NN + SNBLK - 1) / SNBLK;  // 1661 edges per scatter block

__device__ __forceinline__ float lrelu(float v) { return v > 0.f ? v : 0.2f * v; }

// ---------------- shared GEMM body (layer GEMM + attention-logit epilogue) --
// One wave = 4 rows; x-row pointers wave-uniform (SGPR via readfirstlane).
template <int FIN>
__device__ __forceinline__ void gemm_body(int bidx, const float* __restrict__ X,
                                          const float* __restrict__ W,
                                          const float* __restrict__ asrc,
                                          const float* __restrict__ adst,
                                          float* __restrict__ H,
                                          float* __restrict__ als,
                                          float* __restrict__ ald) {
    int j  = threadIdx.x & 63;
    int ty = threadIdx.x >> 6;
    int row = __builtin_amdgcn_readfirstlane(bidx * 16 + ty * 4);
    const float* x0 = X + (size_t)row * FIN;
    const float* x1 = x0 + FIN;
    const float* x2 = x1 + FIN;
    const float* x3 = x2 + FIN;
    float a0 = 0.f, a1 = 0.f, a2 = 0.f, a3 = 0.f;
#pragma unroll
    for (int k = 0; k < FIN; k += 4) {
        float4 xa = *(const float4*)(x0 + k);
        float4 xb = *(const float4*)(x1 + k);
        float4 xc = *(const float4*)(x2 + k);
        float4 xd = *(const float4*)(x3 + k);
        float w0 = W[(k + 0) * 64 + j];
        float w1 = W[(k + 1) * 64 + j];
        float w2 = W[(k + 2) * 64 + j];
        float w3 = W[(k + 3) * 64 + j];
        a0 += xa.x * w0 + xa.y * w1 + xa.z * w2 + xa.w * w3;
        a1 += xb.x * w0 + xb.y * w1 + xb.z * w2 + xb.w * w3;
        a2 += xc.x * w0 + xc.y * w1 + xc.z * w2 + xc.w * w3;
        a3 += xd.x * w0 + xd.y * w1 + xd.z * w2 + xd.w * w3;
    }
    H[(size_t)(row + 0) * 64 + j] = a0;
    H[(size_t)(row + 1) * 64 + j] = a1;
    H[(size_t)(row + 2) * 64 + j] = a2;
    H[(size_t)(row + 3) * 64 + j] = a3;
    float asj = asrc[j], adj = adst[j];
    float accs[4] = {a0, a1, a2, a3};
#pragma unroll
    for (int r = 0; r < 4; r++) {
        float vs = accs[r] * asj;
        float vd = accs[r] * adj;
#pragma unroll
        for (int off = 8; off > 0; off >>= 1) {
            vs += __shfl_xor(vs, off, 64);
            vd += __shfl_xor(vd, off, 64);
        }
        if ((j & 15) == 0) {
            int h = j >> 4;
            als[(size_t)(row + r) * 4 + h] = vs;
            ald[(size_t)(row + r) * 4 + h] = vd;
        }
    }
}

// ---------------- fused count (deg + rank) || layer-0 GEMM ------------------
// Independent work on complementary pipes (atomic/fabric vs VALU/stream).
__global__ __launch_bounds__(256) void k_cg(const int* __restrict__ ei,
                                            int* __restrict__ deg,
                                            int* __restrict__ rank,
                                            const float* __restrict__ X,
                                            const float* __restrict__ W,
                                            const float* __restrict__ asrc,
                                            const float* __restrict__ adst,
                                            float* __restrict__ H,
                                            float* __restrict__ als,
                                            float* __restrict__ ald) {
    if (blockIdx.x < NB_CNT) {
        int i = blockIdx.x * 256 + threadIdx.x;
        if (i < EE + NN) {
            int d = (i < EE) ? ei[EE + i] : (i - EE);
            rank[i] = atomicAdd(&deg[d], 1);
        }
    } else {
        gemm_body<128>(blockIdx.x - NB_CNT, X, W, asrc, adst, H, als, ald);
    }
}

// ---------------- unordered segment alloc + out init ------------------------
// Only per-dst contiguity matters -> wave scan + one atomic bump per wave.
__global__ void k_alloc(const int* __restrict__ deg, int* __restrict__ offs,
                        int* __restrict__ cursor, const float* __restrict__ head_b,
                        float* __restrict__ out) {
    int i = blockIdx.x * blockDim.x + threadIdx.x;
    int lane = threadIdx.x & 63;
    int d = (i < NN) ? deg[i] : 0;
    int incl = d;
#pragma unroll
    for (int off = 1; off < 64; off <<= 1) {
        int t = __shfl_up(incl, off, 64);
        if (lane >= off) incl += t;
    }
    int total = __shfl(incl, 63, 64);
    int base = 0;
    if (lane == 63) base = atomicAdd(cursor, total);
    base = __shfl(base, 63, 64);
    if (i < NN) offs[i] = base + incl - d;
    if (i < GG) out[i] = head_b[0];
}

// ---------------- dst-quartant-phased scatter --------------------------------
// The scatter's cost was random 4B col writes over 6.8 MB (> 4MB/XCD L2 ->
// write-allocate fills) + random offs reads. Phasing by dst quartant makes
// the col slice (1.7 MB) and offs slice (100 KB) L2-resident per phase;
// each block's ~20 KB ei/rank chunk is L2-resident after phase 0. Work per
// phase is uniform streaming with NO dependent chains and NO per-node state
// -- none of the r3/r7/r8 failure modes apply. Soft barrier is bounded-spin,
// locality-only, deadlock-free (proven pattern). rank is precomputed (no new
// atomics here; atomics appear memory-side and would not localize).
__global__ __launch_bounds__(256) void k_scat(const int* __restrict__ ei,
                                              const int* __restrict__ offs,
                                              const int* __restrict__ rank,
                                              int* __restrict__ col,
                                              int* __restrict__ ctr) {
    int b = blockIdx.x, tid = threadIdx.x;
    int lo = b * SCH;
    int hi = lo + SCH; if (hi > EE + NN) hi = EE + NN;
    for (int p = 0; p < NPH; p++) {
        if (tid == 0) {
            __hip_atomic_fetch_add(&ctr[p], 1, __ATOMIC_RELAXED, __HIP_MEMORY_SCOPE_AGENT);
            int polls = 0;
            while (polls++ < 64 &&
                   __hip_atomic_load(&ctr[p], __ATOMIC_RELAXED, __HIP_MEMORY_SCOPE_AGENT) < SNBLK)
                __builtin_amdgcn_s_sleep(1);
        }
        __syncthreads();
        for (int i = lo + tid; i < hi; i += 256) {
            int d = (i < EE) ? ei[EE + i] : (i - EE);
            if ((int)((unsigned)d / QW) == p) {
                int s = (i < EE) ? ei[i] : d;
                col[offs[d] + rank[i]] = s;
            }
        }
        __syncthreads();
    }
}

// ---------------- fused aggregate(L) + GEMM(L+1) ----------------------------
// Round-2 session-best structure verbatim: 8 edges in flight, no-max softmax
// (order-invariant, logits bounded), fused next-layer GEMM from LDS.
__global__ __launch_bounds__(256) void k_aggf(
    const float* __restrict__ H, const float* __restrict__ als,
    const float* __restrict__ ald, const int* __restrict__ offs,
    const int* __restrict__ deg, const int* __restrict__ col,
    const float* __restrict__ bias,          // layer L bias (on aggregated out)
    const float* __restrict__ W,             // layer L+1 weights [64][64]
    const float* __restrict__ asrc,          // layer L+1 a_src [4][16]
    const float* __restrict__ adst,          // layer L+1 a_dst [4][16]
    float* __restrict__ Hn, float* __restrict__ alsn, float* __restrict__ aldn) {
    __shared__ float wl[4096];       // W staged: 16 KB
    __shared__ float xs[16 * 68];    // 16 rows, stride 68 (bank-conflict pad)
    int tid = threadIdx.x;
    int g = tid >> 4;          // group (node) 0..15
    int l = tid & 15;          // lane in group = float4-chunk index 0..15
    int n = blockIdx.x * 16 + g;   // NN % 16 == 0 -> always valid
    int start = offs[n];
    int len = deg[n];
    int hsel = l >> 2;         // head of this lane's channel quad
    float adh = ald[(size_t)n * 4 + hsel];
    const float4* Hp = (const float4*)H + l;

    // stage W while the gather waits on memory
#pragma unroll
    for (int t = 0; t < 4; t++)
        ((float4*)wl)[tid + t * 256] = ((const float4*)W)[tid + t * 256];

    float4 acc = {0.f, 0.f, 0.f, 0.f};
    float ssum = 0.f;
    for (int e = 0; e < len; e += 8) {
        bool  v[8];
        int   s[8];
#pragma unroll
        for (int i = 0; i < 8; i++) {
            v[i] = (e + i < len);
            s[i] = v[i] ? col[start + e + i] : 0;
        }
        float  w[8];
        float4 hr[8];
#pragma unroll
        for (int i = 0; i < 8; i++) {
            float a = als[(size_t)s[i] * 4 + hsel];
            hr[i] = Hp[(size_t)s[i] * 16];
            float ev = lrelu(a + adh);
            w[i] = v[i] ? __expf(ev) : 0.f;
        }
#pragma unroll
        for (int i = 0; i < 8; i++) {
            ssum  += w[i];
            acc.x = fmaf(w[i], hr[i].x, acc.x);
            acc.y = fmaf(w[i], hr[i].y, acc.y);
            acc.z = fmaf(w[i], hr[i].z, acc.z);
            acc.w = fmaf(w[i], hr[i].w, acc.w);
        }
    }
    float inv = 1.f / (ssum + 1e-16f);
    float4 b4 = ((const float4*)bias)[l];
    float* xr = xs + g * 68 + 4 * l;
    xr[0] = fmaxf(acc.x * inv + b4.x, 0.f);
    xr[1] = fmaxf(acc.y * inv + b4.y, 0.f);
    xr[2] = fmaxf(acc.z * inv + b4.z, 0.f);
    xr[3] = fmaxf(acc.w * inv + b4.w, 0.f);

    __syncthreads();   // xs + wl ready

    // ---- GEMM: thread (g,l) -> row n, output channels 4l..4l+3 ------------
    float4 o = {0.f, 0.f, 0.f, 0.f};
    const float* xrow = xs + g * 68;
    const float* wcol = wl + 4 * l;
#pragma unroll
    for (int k = 0; k < 64; k += 4) {
        float4 xv = *(const float4*)(xrow + k);
        float4 w0 = *(const float4*)(wcol + (k + 0) * 64);
        float4 w1 = *(const float4*)(wcol + (k + 1) * 64);
        float4 w2 = *(const float4*)(wcol + (k + 2) * 64);
        float4 w3 = *(const float4*)(wcol + (k + 3) * 64);
        o.x += xv.x * w0.x + xv.y * w1.x + xv.z * w2.x + xv.w * w3.x;
        o.y += xv.x * w0.y + xv.y * w1.y + xv.z * w2.y + xv.w * w3.y;
        o.z += xv.x * w0.z + xv.y * w1.z + xv.z * w2.z + xv.w * w3.z;
        o.w += xv.x * w0.w + xv.y * w1.w + xv.z * w2.w + xv.w * w3.w;
    }
    ((float4*)Hn)[(size_t)n * 16 + l] = o;

    // attention logits for layer L+1: channels 4l..4l+3 are all in head l>>2
    float4 av = ((const float4*)asrc)[l];
    float4 dv = ((const float4*)adst)[l];
    float vs = o.x * av.x + o.y * av.y + o.z * av.z + o.w * av.w;
    float vd = o.x * dv.x + o.y * dv.y + o.z * dv.z + o.w * dv.w;
    vs += __shfl_xor(vs, 1, 16); vs += __shfl_xor(vs, 2, 16);
    vd += __shfl_xor(vd, 1, 16); vd += __shfl_xor(vd, 2, 16);
    if ((l & 3) == 0) {
        int h = l >> 2;
        alsn[(size_t)n * 4 + h] = vs;
        aldn[(size_t)n * 4 + h] = vd;
    }
}

// ---------------- last layer: aggregate + head projection + pool ------------
__global__ __launch_bounds__(256) void k_aggl(
    const float* __restrict__ H, const float* __restrict__ als,
    const float* __restrict__ ald, const int* __restrict__ offs,
    const int* __restrict__ deg, const int* __restrict__ col,
    const float* __restrict__ bias, const int* __restrict__ batch,
    const float* __restrict__ hw, float* __restrict__ out) {
    int tid = threadIdx.x;
    int g = tid >> 4;
    int l = tid & 15;
    int n = blockIdx.x * 16 + g;
    int start = offs[n];
    int len = deg[n];
    int hsel = l >> 2;
    float adh = ald[(size_t)n * 4 + hsel];
    const float4* Hp = (const float4*)H + l;

    float4 acc = {0.f, 0.f, 0.f, 0.f};
    float ssum = 0.f;
    for (int e = 0; e < len; e += 8) {
        bool  v[8];
        int   s[8];
#pragma unroll
        for (int i = 0; i < 8; i++) {
            v[i] = (e + i < len);
            s[i] = v[i] ? col[start + e + i] : 0;
        }
        float  w[8];
        float4 hr[8];
#pragma unroll
        for (int i = 0; i < 8; i++) {
            float a = als[(size_t)s[i] * 4 + hsel];
            hr[i] = Hp[(size_t)s[i] * 16];
            float ev = lrelu(a + adh);
            w[i] = v[i] ? __expf(ev) : 0.f;
        }
#pragma unroll
        for (int i = 0; i < 8; i++) {
            ssum  += w[i];
            acc.x = fmaf(w[i], hr[i].x, acc.x);
            acc.y = fmaf(w[i], hr[i].y, acc.y);
            acc.z = fmaf(w[i], hr[i].z, acc.z);
            acc.w = fmaf(w[i], hr[i].w, acc.w);
        }
    }
    float inv = 1.f / (ssum + 1e-16f);
    float4 b4 = ((const float4*)bias)[l];
    float4 w4 = ((const float4*)hw)[l];
    float t = fmaxf(acc.x * inv + b4.x, 0.f) * w4.x
            + fmaxf(acc.y * inv + b4.y, 0.f) * w4.y
            + fmaxf(acc.z * inv + b4.z, 0.f) * w4.z
            + fmaxf(acc.w * inv + b4.w, 0.f) * w4.w;
#pragma unroll
    for (int off = 8; off > 0; off >>= 1) t += __shfl_xor(t, off, 16);
    if (l == 0) atomicAdd(&out[batch[n]], t);
}

// ---------------- launch -----------------------------------------------------
extern "C" void kernel_launch(void* const* d_in, const int* in_sizes, int n_in,
                              void* d_out, int out_size, void* d_ws, size_t ws_size,
                              hipStream_t stream) {
    const float* x     = (const float*)d_in[0];
    const int*   ei    = (const int*)d_in[1];
    const int*   batch = (const int*)d_in[2];
    const float* Wm[3] = {(const float*)d_in[3], (const float*)d_in[7],  (const float*)d_in[11]};
    const float* As[3] = {(const float*)d_in[4], (const float*)d_in[8],  (const float*)d_in[12]};
    const float* Ad[3] = {(const float*)d_in[5], (const float*)d_in[9],  (const float*)d_in[13]};
    const float* Bb[3] = {(const float*)d_in[6], (const float*)d_in[10], (const float*)d_in[14]};
    const float* hw = (const float*)d_in[15];
    const float* hb = (const float*)d_in[16];
    float* out = (float*)d_out;

    uint8_t* w = (uint8_t*)d_ws;
    auto alloc = [&](size_t bytes) -> void* {
        void* p = (void*)w;
        w += (bytes + 255) & ~(size_t)255;
        return p;
    };
    float* H    = (float*)alloc((size_t)NN * 64 * 4);   // ping (gather source)
    float* Bf   = (float*)alloc((size_t)NN * 64 * 4);   // pong
    float* als  = (float*)alloc((size_t)NN * 4 * 4);
    float* ald  = (float*)alloc((size_t)NN * 4 * 4);
    float* als2 = (float*)alloc((size_t)NN * 4 * 4);
    float* ald2 = (float*)alloc((size_t)NN * 4 * 4);
    int*   deg  = (int*)alloc((size_t)(NN + 64) * 4);   // + cursor + phase ctrs
    int*   offs = (int*)alloc((size_t)NN * 4);
    int*   rank = (int*)alloc((size_t)(EE + NN) * 4);
    int*   col  = (int*)alloc((size_t)(EE + NN) * 4);

    int* cursor = deg + NN;
    int* ctr    = cursor + 8;     // 4 scatter phase counters

    hipMemsetAsync(deg, 0, (size_t)(NN + 64) * 4, stream);

    // count (deg+rank) || layer-0 GEMM in one grid
    k_cg<<<NB_CNT + NB_GEMM, 256, 0, stream>>>(ei, deg, rank,
                                               x, Wm[0], As[0], Ad[0], H, als, ald);
    k_alloc<<<(NN + 255) / 256, 256, 0, stream>>>(deg, offs, cursor, hb, out);
    k_scat <<<SNBLK, 256, 0, stream>>>(ei, offs, rank, col, ctr);

    k_aggf<<<NN / 16, 256, 0, stream>>>(H,  als,  ald,  offs, deg, col, Bb[0],
                                        Wm[1], As[1], Ad[1], Bf, als2, ald2);
    k_aggf<<<NN / 16, 256, 0, stream>>>(Bf, als2, ald2, offs, deg, col, Bb[1],
                                        Wm[2], As[2], Ad[2], H, als, ald);
    k_aggl<<<NN / 16, 256, 0, stream>>>(H,  als,  ald,  offs, deg, col, Bb[2],
                                        batch, hw, out);
}

// Round 10
// 535.071 us; speedup vs baseline: 4.9299x; 1.3724x over previous
//
#include <hip/hip_runtime.h>
#include <hip/hip_bf16.h>
#include <hip/hip_fp16.h>
#include <cstdint>
#include <cstddef>

#define NN 100000
#define EE 1600000
#define GG 2048

constexpr int NB_CNT  = (EE + NN + 255) / 256;  // 6641 count blocks
constexpr int NB_GEMM = NN / 16;                // 6250 gemm blocks

__device__ __forceinline__ float lrelu(float v) { return v > 0.f ? v : 0.2f * v; }

// ---------------- shared GEMM body (layer GEMM + attention-logit epilogue) --
// One wave = 4 rows; x-row pointers wave-uniform (SGPR via readfirstlane).
template <int FIN>
__device__ __forceinline__ void gemm_body(int bidx, const float* __restrict__ X,
                                          const float* __restrict__ W,
                                          const float* __restrict__ asrc,
                                          const float* __restrict__ adst,
                                          float* __restrict__ H,
                                          float* __restrict__ als,
                                          float* __restrict__ ald) {
    int j  = threadIdx.x & 63;
    int ty = threadIdx.x >> 6;
    int row = __builtin_amdgcn_readfirstlane(bidx * 16 + ty * 4);
    const float* x0 = X + (size_t)row * FIN;
    const float* x1 = x0 + FIN;
    const float* x2 = x1 + FIN;
    const float* x3 = x2 + FIN;
    float a0 = 0.f, a1 = 0.f, a2 = 0.f, a3 = 0.f;
#pragma unroll
    for (int k = 0; k < FIN; k += 4) {
        float4 xa = *(const float4*)(x0 + k);
        float4 xb = *(const float4*)(x1 + k);
        float4 xc = *(const float4*)(x2 + k);
        float4 xd = *(const float4*)(x3 + k);
        float w0 = W[(k + 0) * 64 + j];
        float w1 = W[(k + 1) * 64 + j];
        float w2 = W[(k + 2) * 64 + j];
        float w3 = W[(k + 3) * 64 + j];
        a0 += xa.x * w0 + xa.y * w1 + xa.z * w2 + xa.w * w3;
        a1 += xb.x * w0 + xb.y * w1 + xb.z * w2 + xb.w * w3;
        a2 += xc.x * w0 + xc.y * w1 + xc.z * w2 + xc.w * w3;
        a3 += xd.x * w0 + xd.y * w1 + xd.z * w2 + xd.w * w3;
    }
    H[(size_t)(row + 0) * 64 + j] = a0;
    H[(size_t)(row + 1) * 64 + j] = a1;
    H[(size_t)(row + 2) * 64 + j] = a2;
    H[(size_t)(row + 3) * 64 + j] = a3;
    float asj = asrc[j], adj = adst[j];
    float accs[4] = {a0, a1, a2, a3};
#pragma unroll
    for (int r = 0; r < 4; r++) {
        float vs = accs[r] * asj;
        float vd = accs[r] * adj;
#pragma unroll
        for (int off = 8; off > 0; off >>= 1) {
            vs += __shfl_xor(vs, off, 64);
            vd += __shfl_xor(vd, off, 64);
        }
        if ((j & 15) == 0) {
            int h = j >> 4;
            als[(size_t)(row + r) * 4 + h] = vs;
            ald[(size_t)(row + r) * 4 + h] = vd;
        }
    }
}

// ---------------- fused count (deg + rank) || layer-0 GEMM ------------------
// Independent work on complementary pipes (atomic/fabric vs VALU/stream);
// the GEMM hides inside the count's memory-side atomic service time.
__global__ __launch_bounds__(256) void k_cg(const int* __restrict__ ei,
                                            int* __restrict__ deg,
                                            int* __restrict__ rank,
                                            const float* __restrict__ X,
                                            const float* __restrict__ W,
                                            const float* __restrict__ asrc,
                                            const float* __restrict__ adst,
                                            float* __restrict__ H,
                                            float* __restrict__ als,
                                            float* __restrict__ ald) {
    if (blockIdx.x < NB_CNT) {
        int i = blockIdx.x * 256 + threadIdx.x;
        if (i < EE + NN) {
            int d = (i < EE) ? ei[EE + i] : (i - EE);
            rank[i] = atomicAdd(&deg[d], 1);
        }
    } else {
        gemm_body<128>(blockIdx.x - NB_CNT, X, W, asrc, adst, H, als, ald);
    }
}

// ---------------- unordered segment alloc + out init ------------------------
// Only per-dst contiguity matters -> wave scan + one atomic bump per wave.
__global__ void k_alloc(const int* __restrict__ deg, int* __restrict__ offs,
                        int* __restrict__ cursor, const float* __restrict__ head_b,
                        float* __restrict__ out) {
    int i = blockIdx.x * blockDim.x + threadIdx.x;
    int lane = threadIdx.x & 63;
    int d = (i < NN) ? deg[i] : 0;
    int incl = d;
#pragma unroll
    for (int off = 1; off < 64; off <<= 1) {
        int t = __shfl_up(incl, off, 64);
        if (lane >= off) incl += t;
    }
    int total = __shfl(incl, 63, 64);
    int base = 0;
    if (lane == 63) base = atomicAdd(cursor, total);
    base = __shfl(base, 63, 64);
    if (i < NN) offs[i] = base + incl - d;
    if (i < GG) out[i] = head_b[0];
}

// ---------------- scatter (plain; measured best) ----------------------------
__global__ void k_scatter(const int* __restrict__ ei, const int* __restrict__ offs,
                          const int* __restrict__ rank, int* __restrict__ col) {
    int i = blockIdx.x * blockDim.x + threadIdx.x;
    if (i >= EE + NN) return;
    int s, d;
    if (i < EE) { s = ei[i]; d = ei[EE + i]; } else { s = d = i - EE; }
    col[offs[d] + rank[i]] = s;
}

// ---------------- fused aggregate(L) + GEMM(L+1) ----------------------------
// Session-best gather structure (round 2): 8 edges in flight, no-max softmax
// (order-invariant, logits bounded ~|3|), fused next-layer GEMM from LDS.
// The gather runs at the compulsory per-XCD fill floor (~237 MB L2-miss
// traffic) at the random-granule service rate (~2.4 TB/s) -- invariant
// across 5 structural variants (r1,r2,r3,r7,r8).
__global__ __launch_bounds__(256) void k_aggf(
    const float* __restrict__ H, const float* __restrict__ als,
    const float* __restrict__ ald, const int* __restrict__ offs,
    const int* __restrict__ deg, const int* __restrict__ col,
    const float* __restrict__ bias,          // layer L bias (on aggregated out)
    const float* __restrict__ W,             // layer L+1 weights [64][64]
    const float* __restrict__ asrc,          // layer L+1 a_src [4][16]
    const float* __restrict__ adst,          // layer L+1 a_dst [4][16]
    float* __restrict__ Hn, float* __restrict__ alsn, float* __restrict__ aldn) {
    __shared__ float wl[4096];       // W staged: 16 KB
    __shared__ float xs[16 * 68];    // 16 rows, stride 68 (bank-conflict pad)
    int tid = threadIdx.x;
    int g = tid >> 4;          // group (node) 0..15
    int l = tid & 15;          // lane in group = float4-chunk index 0..15
    int n = blockIdx.x * 16 + g;   // NN % 16 == 0 -> always valid
    int start = offs[n];
    int len = deg[n];
    int hsel = l >> 2;         // head of this lane's channel quad
    float adh = ald[(size_t)n * 4 + hsel];
    const float4* Hp = (const float4*)H + l;

    // stage W while the gather waits on memory
#pragma unroll
    for (int t = 0; t < 4; t++)
        ((float4*)wl)[tid + t * 256] = ((const float4*)W)[tid + t * 256];

    float4 acc = {0.f, 0.f, 0.f, 0.f};
    float ssum = 0.f;
    for (int e = 0; e < len; e += 8) {
        bool  v[8];
        int   s[8];
#pragma unroll
        for (int i = 0; i < 8; i++) {
            v[i] = (e + i < len);
            s[i] = v[i] ? col[start + e + i] : 0;
        }
        float  w[8];
        float4 hr[8];
#pragma unroll
        for (int i = 0; i < 8; i++) {
            float a = als[(size_t)s[i] * 4 + hsel];
            hr[i] = Hp[(size_t)s[i] * 16];
            float ev = lrelu(a + adh);
            w[i] = v[i] ? __expf(ev) : 0.f;
        }
#pragma unroll
        for (int i = 0; i < 8; i++) {
            ssum  += w[i];
            acc.x = fmaf(w[i], hr[i].x, acc.x);
            acc.y = fmaf(w[i], hr[i].y, acc.y);
            acc.z = fmaf(w[i], hr[i].z, acc.z);
            acc.w = fmaf(w[i], hr[i].w, acc.w);
        }
    }
    float inv = 1.f / (ssum + 1e-16f);
    float4 b4 = ((const float4*)bias)[l];
    float* xr = xs + g * 68 + 4 * l;
    xr[0] = fmaxf(acc.x * inv + b4.x, 0.f);
    xr[1] = fmaxf(acc.y * inv + b4.y, 0.f);
    xr[2] = fmaxf(acc.z * inv + b4.z, 0.f);
    xr[3] = fmaxf(acc.w * inv + b4.w, 0.f);

    __syncthreads();   // xs + wl ready

    // ---- GEMM: thread (g,l) -> row n, output channels 4l..4l+3 ------------
    float4 o = {0.f, 0.f, 0.f, 0.f};
    const float* xrow = xs + g * 68;
    const float* wcol = wl + 4 * l;
#pragma unroll
    for (int k = 0; k < 64; k += 4) {
        float4 xv = *(const float4*)(xrow + k);
        float4 w0 = *(const float4*)(wcol + (k + 0) * 64);
        float4 w1 = *(const float4*)(wcol + (k + 1) * 64);
        float4 w2 = *(const float4*)(wcol + (k + 2) * 64);
        float4 w3 = *(const float4*)(wcol + (k + 3) * 64);
        o.x += xv.x * w0.x + xv.y * w1.x + xv.z * w2.x + xv.w * w3.x;
        o.y += xv.x * w0.y + xv.y * w1.y + xv.z * w2.y + xv.w * w3.y;
        o.z += xv.x * w0.z + xv.y * w1.z + xv.z * w2.z + xv.w * w3.z;
        o.w += xv.x * w0.w + xv.y * w1.w + xv.z * w2.w + xv.w * w3.w;
    }
    ((float4*)Hn)[(size_t)n * 16 + l] = o;

    // attention logits for layer L+1: channels 4l..4l+3 are all in head l>>2
    float4 av = ((const float4*)asrc)[l];
    float4 dv = ((const float4*)adst)[l];
    float vs = o.x * av.x + o.y * av.y + o.z * av.z + o.w * av.w;
    float vd = o.x * dv.x + o.y * dv.y + o.z * dv.z + o.w * dv.w;
    vs += __shfl_xor(vs, 1, 16); vs += __shfl_xor(vs, 2, 16);
    vd += __shfl_xor(vd, 1, 16); vd += __shfl_xor(vd, 2, 16);
    if ((l & 3) == 0) {
        int h = l >> 2;
        alsn[(size_t)n * 4 + h] = vs;
        aldn[(size_t)n * 4 + h] = vd;
    }
}

// ---------------- last layer: aggregate + head projection + pool ------------
__global__ __launch_bounds__(256) void k_aggl(
    const float* __restrict__ H, const float* __restrict__ als,
    const float* __restrict__ ald, const int* __restrict__ offs,
    const int* __restrict__ deg, const int* __restrict__ col,
    const float* __restrict__ bias, const int* __restrict__ batch,
    const float* __restrict__ hw, float* __restrict__ out) {
    int tid = threadIdx.x;
    int g = tid >> 4;
    int l = tid & 15;
    int n = blockIdx.x * 16 + g;
    int start = offs[n];
    int len = deg[n];
    int hsel = l >> 2;
    float adh = ald[(size_t)n * 4 + hsel];
    const float4* Hp = (const float4*)H + l;

    float4 acc = {0.f, 0.f, 0.f, 0.f};
    float ssum = 0.f;
    for (int e = 0; e < len; e += 8) {
        bool  v[8];
        int   s[8];
#pragma unroll
        for (int i = 0; i < 8; i++) {
            v[i] = (e + i < len);
            s[i] = v[i] ? col[start + e + i] : 0;
        }
        float  w[8];
        float4 hr[8];
#pragma unroll
        for (int i = 0; i < 8; i++) {
            float a = als[(size_t)s[i] * 4 + hsel];
            hr[i] = Hp[(size_t)s[i] * 16];
            float ev = lrelu(a + adh);
            w[i] = v[i] ? __expf(ev) : 0.f;
        }
#pragma unroll
        for (int i = 0; i < 8; i++) {
            ssum  += w[i];
            acc.x = fmaf(w[i], hr[i].x, acc.x);
            acc.y = fmaf(w[i], hr[i].y, acc.y);
            acc.z = fmaf(w[i], hr[i].z, acc.z);
            acc.w = fmaf(w[i], hr[i].w, acc.w);
        }
    }
    float inv = 1.f / (ssum + 1e-16f);
    float4 b4 = ((const float4*)bias)[l];
    float4 w4 = ((const float4*)hw)[l];
    float t = fmaxf(acc.x * inv + b4.x, 0.f) * w4.x
            + fmaxf(acc.y * inv + b4.y, 0.f) * w4.y
            + fmaxf(acc.z * inv + b4.z, 0.f) * w4.z
            + fmaxf(acc.w * inv + b4.w, 0.f) * w4.w;
#pragma unroll
    for (int off = 8; off > 0; off >>= 1) t += __shfl_xor(t, off, 16);
    if (l == 0) atomicAdd(&out[batch[n]], t);
}

// ---------------- launch -----------------------------------------------------
extern "C" void kernel_launch(void* const* d_in, const int* in_sizes, int n_in,
                              void* d_out, int out_size, void* d_ws, size_t ws_size,
                              hipStream_t stream) {
    const float* x     = (const float*)d_in[0];
    const int*   ei    = (const int*)d_in[1];
    const int*   batch = (const int*)d_in[2];
    const float* Wm[3] = {(const float*)d_in[3], (const float*)d_in[7],  (const float*)d_in[11]};
    const float* As[3] = {(const float*)d_in[4], (const float*)d_in[8],  (const float*)d_in[12]};
    const float* Ad[3] = {(const float*)d_in[5], (const float*)d_in[9],  (const float*)d_in[13]};
    const float* Bb[3] = {(const float*)d_in[6], (const float*)d_in[10], (const float*)d_in[14]};
    const float* hw = (const float*)d_in[15];
    const float* hb = (const float*)d_in[16];
    float* out = (float*)d_out;

    uint8_t* w = (uint8_t*)d_ws;
    auto alloc = [&](size_t bytes) -> void* {
        void* p = (void*)w;
        w += (bytes + 255) & ~(size_t)255;
        return p;
    };
    float* H    = (float*)alloc((size_t)NN * 64 * 4);   // ping (gather source)
    float* Bf   = (float*)alloc((size_t)NN * 64 * 4);   // pong
    float* als  = (float*)alloc((size_t)NN * 4 * 4);
    float* ald  = (float*)alloc((size_t)NN * 4 * 4);
    float* als2 = (float*)alloc((size_t)NN * 4 * 4);
    float* ald2 = (float*)alloc((size_t)NN * 4 * 4);
    int*   deg  = (int*)alloc((size_t)(NN + 64) * 4);   // + cursor word
    int*   offs = (int*)alloc((size_t)NN * 4);
    int*   rank = (int*)alloc((size_t)(EE + NN) * 4);
    int*   col  = (int*)alloc((size_t)(EE + NN) * 4);

    int* cursor = deg + NN;

    hipMemsetAsync(deg, 0, (size_t)(NN + 64) * 4, stream);

    int eb = (EE + NN + 255) / 256;
    int nb = (NN + 255) / 256;
    // count (deg+rank) || layer-0 GEMM in one grid
    k_cg<<<NB_CNT + NB_GEMM, 256, 0, stream>>>(ei, deg, rank,
                                               x, Wm[0], As[0], Ad[0], H, als, ald);
    k_alloc  <<<nb, 256, 0, stream>>>(deg, offs, cursor, hb, out);
    k_scatter<<<eb, 256, 0, stream>>>(ei, offs, rank, col);

    k_aggf<<<NN / 16, 256, 0, stream>>>(H,  als,  ald,  offs, deg, col, Bb[0],
                                        Wm[1], As[1], Ad[1], Bf, als2, ald2);
    k_aggf<<<NN / 16, 256, 0, stream>>>(Bf, als2, ald2, offs, deg, col, Bb[1],
                                        Wm[2], As[2], Ad[2], H, als, ald);
    k_aggl<<<NN / 16, 256, 0, stream>>>(H,  als,  ald,  offs, deg, col, Bb[2],
                                        batch, hw, out);
}